// Round 8
// baseline (609.316 us; speedup 1.0000x reference)
//
#include <hip/hip_runtime.h>
#include <hip/hip_bf16.h>

#define H   2048
#define E   16
#define TK  4
#define I2  1536
#define IN  768

typedef __attribute__((ext_vector_type(8))) short bf16x8;
typedef __attribute__((ext_vector_type(4))) float f32x4;

__device__ __forceinline__ short f2bf(float f) {
  union { float f; unsigned u; } v; v.f = f;
  unsigned r = (v.u + 0x7FFFu + ((v.u >> 16) & 1u)) >> 16;
  return (short)r;
}

__device__ __forceinline__ void gload16(const ushort* g, ushort* l) {
  __builtin_amdgcn_global_load_lds(
      (const __attribute__((address_space(1))) void*)g,
      (__attribute__((address_space(3))) void*)l, 16, 0, 0);
}

// ---------------- router: logits -> top4 -> normalized weights -------------
__global__ __launch_bounds__(256) void router_kernel(
    const float* __restrict__ x, const float* __restrict__ rw,
    int* __restrict__ cnt, int* __restrict__ tke, float* __restrict__ tkw) {
  const int t = blockIdx.x;
  const int lane = threadIdx.x & 63;
  const int wave = threadIdx.x >> 6;
  __shared__ float logits[E];
  const float* xr = x + (size_t)t * H;
  for (int ee = 0; ee < 4; ++ee) {
    const int e = wave * 4 + ee;
    const float* w = rw + (size_t)e * H;
    float s = 0.f;
    for (int k = lane; k < H; k += 64) s += xr[k] * w[k];
    for (int off = 32; off > 0; off >>= 1) s += __shfl_down(s, off);
    if (lane == 0) logits[e] = s;
  }
  __syncthreads();
  if (threadIdx.x == 0) {
    float l[E];
    for (int e = 0; e < E; ++e) l[e] = logits[e];
    int idx[TK]; float v[TK];
    for (int k = 0; k < TK; ++k) {
      int bi = 0; float bv = -3.4e38f;
      for (int e = 0; e < E; ++e) if (l[e] > bv) { bv = l[e]; bi = e; }
      idx[k] = bi; v[k] = bv; l[bi] = -3.4e38f;
    }
    const float m = v[0];
    float p[TK]; float z = 0.f;
    for (int k = 0; k < TK; ++k) { p[k] = expf(v[k] - m); z += p[k]; }
    const float rz = 1.f / z;
    for (int k = 0; k < TK; ++k) {
      tke[t * TK + k] = idx[k];
      tkw[t * TK + k] = p[k] * rz;
      atomicAdd(&cnt[idx[k]], 1);
    }
  }
}

__global__ void scan_kernel(const int* __restrict__ cnt, int* __restrict__ offs) {
  if (threadIdx.x == 0) {
    int s = 0;
    for (int e = 0; e < E; ++e) { offs[e] = s; s += cnt[e]; }
    offs[E] = s;
  }
}

__global__ __launch_bounds__(256) void scatter_kernel(
    const int* __restrict__ tke, const float* __restrict__ tkw,
    const int* __restrict__ offs, int* __restrict__ cursor,
    int* __restrict__ tok, float* __restrict__ pw) {
  const int i = blockIdx.x * 256 + threadIdx.x;
  const int e = tke[i];
  const int pos = atomicAdd(&cursor[e], 1);
  const int dst = offs[e] + pos;
  tok[dst] = i >> 2;
  pw[dst] = tkw[i];
}

// ---------------- prep: transpose + cvt fp32 [R][C] -> bf16 [C][R] ---------
__global__ __launch_bounds__(256) void tcvt_kernel(
    const float* __restrict__ in, ushort* __restrict__ out, int R, int C) {
  const size_t eb = (size_t)blockIdx.z * R * C;
  const int r0 = blockIdx.y * 64, c0 = blockIdx.x * 64;
  __shared__ ushort t[64][68];
  const int tid = threadIdx.x;
  const int rr = tid >> 4;
  const int cc4 = (tid & 15) * 4;
#pragma unroll
  for (int i = 0; i < 4; ++i) {
    const int r = i * 16 + rr;
    float4 v = *(const float4*)(in + eb + (size_t)(r0 + r) * C + c0 + cc4);
    t[cc4 + 0][r] = (ushort)f2bf(v.x); t[cc4 + 1][r] = (ushort)f2bf(v.y);
    t[cc4 + 2][r] = (ushort)f2bf(v.z); t[cc4 + 3][r] = (ushort)f2bf(v.w);
  }
  __syncthreads();
  const int cr = tid >> 4;
  const int rr4 = (tid & 15) * 4;
#pragma unroll
  for (int i = 0; i < 4; ++i) {
    const int c = i * 16 + cr;
    ushort4 o;
    o.x = t[c][rr4]; o.y = t[c][rr4 + 1]; o.z = t[c][rr4 + 2]; o.w = t[c][rr4 + 3];
    *(ushort4*)(out + eb + (size_t)(c0 + c) * R + r0 + rr4) = o;
  }
}

__global__ __launch_bounds__(256) void xcvt_kernel(
    const float* __restrict__ x, ushort* __restrict__ xb, int n4) {
  const int i = blockIdx.x * 256 + threadIdx.x;
  if (i < n4) {
    float4 v = ((const float4*)x)[i];
    ushort4 o;
    o.x = (ushort)f2bf(v.x); o.y = (ushort)f2bf(v.y);
    o.z = (ushort)f2bf(v.z); o.w = (ushort)f2bf(v.w);
    ((ushort4*)xb)[i] = o;
  }
}

// ---------------- gateup3: 128-token tile bf16 GEMM + silu epilogue --------
// grid (IN/64, T/128, E), 4 waves (2m x 2n). Wave: 64 rows x 32 cols of gate
// AND 32 cols of up. BK=64, 2 s-halves: per s 8 ds_read_b128 : 16 MFMA.
__global__ __launch_bounds__(256) void gateup3_kernel(
    const ushort* __restrict__ xb, const ushort* __restrict__ gupT,
    const int* __restrict__ offs, const int* __restrict__ tok,
    const float* __restrict__ pw, ushort* __restrict__ h, int P) {
  const int e = blockIdx.z;
  const int base = offs[e];
  const int Ce = offs[e + 1] - base;
  const int m0 = blockIdx.y * 128;
  if (m0 >= Ce) return;
  const int n0 = blockIdx.x * 64;
  __shared__ ushort As[128 * 64];
  __shared__ ushort Bg[64 * 64];
  __shared__ ushort Bu[64 * 64];
  const int tid = threadIdx.x;
  const int lane = tid & 63, wave = tid >> 6;
  const int wm = wave >> 1, wn = wave & 1;
  const int srow = lane >> 3;                    // 0..7 == row&7 of staged row
  const int schunk = ((lane & 7) ^ srow) << 3;   // pre-swizzled k-chunk (elems)

  // A staging: wave covers rows [wave*32, wave*32+32), 4 gloads of 8 rows
  const ushort* aS[4]; ushort* aD[4];
#pragma unroll
  for (int i = 0; i < 4; ++i) {
    int ar = base + m0 + wave * 32 + i * 8 + srow;
    if (ar >= P) ar = P - 1;
    aS[i] = xb + (size_t)tok[ar] * H + schunk;
    aD[i] = As + (wave * 32 + i * 8) * 64;
  }
  // B staging: each 64-col panel, wave covers 16 cols, 2 gloads each
  const size_t gB = (size_t)e * I2 * H;
  const ushort* gS[2]; ushort* gD[2];
  const ushort* uS[2]; ushort* uD[2];
#pragma unroll
  for (int i = 0; i < 2; ++i) {
    const int c = wave * 16 + i * 8 + srow;
    gS[i] = gupT + gB + (size_t)(n0 + c) * H + schunk;
    uS[i] = gupT + gB + (size_t)(IN + n0 + c) * H + schunk;
    gD[i] = Bg + (wave * 16 + i * 8) * 64;
    uD[i] = Bu + (wave * 16 + i * 8) * 64;
  }

  const int la = lane & 15, q = lane >> 4;
  int aoff[2][4], boff[2][2];
#pragma unroll
  for (int s = 0; s < 2; ++s) {
    const int qq = s * 4 + q;
    const int slot = (qq ^ (la & 7)) << 3;       // rows ≡ la (mod 8)
#pragma unroll
    for (int fm = 0; fm < 4; ++fm)
      aoff[s][fm] = (wm * 64 + fm * 16 + la) * 64 + slot;
#pragma unroll
    for (int fn = 0; fn < 2; ++fn)
      boff[s][fn] = (wn * 32 + fn * 16 + la) * 64 + slot;
  }

  f32x4 accg[4][2], accu[4][2];
#pragma unroll
  for (int a = 0; a < 4; ++a)
#pragma unroll
    for (int b = 0; b < 2; ++b) {
      accg[a][b] = (f32x4){0.f, 0.f, 0.f, 0.f};
      accu[a][b] = (f32x4){0.f, 0.f, 0.f, 0.f};
    }

  for (int k0 = 0; k0 < H; k0 += 64) {
#pragma unroll
    for (int i = 0; i < 4; ++i) { gload16(aS[i], aD[i]); aS[i] += 64; }
#pragma unroll
    for (int i = 0; i < 2; ++i) {
      gload16(gS[i], gD[i]); gS[i] += 64;
      gload16(uS[i], uD[i]); uS[i] += 64;
    }
    __syncthreads();
#pragma unroll
    for (int s = 0; s < 2; ++s) {
      bf16x8 af[4], gf[2], uf[2];
#pragma unroll
      for (int fm = 0; fm < 4; ++fm) af[fm] = *(const bf16x8*)&As[aoff[s][fm]];
#pragma unroll
      for (int fn = 0; fn < 2; ++fn) {
        gf[fn] = *(const bf16x8*)&Bg[boff[s][fn]];
        uf[fn] = *(const bf16x8*)&Bu[boff[s][fn]];
      }
#pragma unroll
      for (int fm = 0; fm < 4; ++fm)
#pragma unroll
        for (int fn = 0; fn < 2; ++fn) {
          accg[fm][fn] = __builtin_amdgcn_mfma_f32_16x16x32_bf16(af[fm], gf[fn], accg[fm][fn], 0, 0, 0);
          accu[fm][fn] = __builtin_amdgcn_mfma_f32_16x16x32_bf16(af[fm], uf[fn], accu[fm][fn], 0, 0, 0);
        }
    }
    __syncthreads();
  }

#pragma unroll
  for (int fm = 0; fm < 4; ++fm) {
    const int rbase = wm * 64 + fm * 16 + (q << 2);
#pragma unroll
    for (int j = 0; j < 4; ++j) {
      const int row = m0 + rbase + j;
      if (row < Ce) {
        const float wgt = pw[base + row];
#pragma unroll
        for (int fn = 0; fn < 2; ++fn) {
          const float g = accg[fm][fn][j];
          const float u = accu[fm][fn][j];
          const float hv = (g / (1.f + expf(-g))) * u * wgt;
          const int col = n0 + wn * 32 + fn * 16 + la;
          h[(size_t)(base + row) * IN + col] = (ushort)f2bf(hv);
        }
      }
    }
  }
}

// ---------------- down3: 128x128 tile bf16 GEMM, atomicAdd epilogue --------
// grid (H/128, T/128, E), 4 waves (2m x 2n), wave 64x64. BK=64, K=768.
__global__ __launch_bounds__(256) void down3_kernel(
    const ushort* __restrict__ h, const ushort* __restrict__ dT,
    const int* __restrict__ offs, const int* __restrict__ tok,
    float* __restrict__ out, int P) {
  const int e = blockIdx.z;
  const int base = offs[e];
  const int Ce = offs[e + 1] - base;
  const int m0 = blockIdx.y * 128;
  if (m0 >= Ce) return;
  const int n0 = blockIdx.x * 128;
  __shared__ ushort As[128 * 64];
  __shared__ ushort Bs[128 * 64];
  const int tid = threadIdx.x;
  const int lane = tid & 63, wave = tid >> 6;
  const int wm = wave >> 1, wn = wave & 1;
  const int srow = lane >> 3;
  const int schunk = ((lane & 7) ^ srow) << 3;

  const ushort* aS[4]; ushort* aD[4];
  const ushort* bS[4]; ushort* bD[4];
#pragma unroll
  for (int i = 0; i < 4; ++i) {
    int ar = base + m0 + wave * 32 + i * 8 + srow;
    if (ar >= P) ar = P - 1;
    aS[i] = h + (size_t)ar * IN + schunk;
    aD[i] = As + (wave * 32 + i * 8) * 64;
    const int c = n0 + wave * 32 + i * 8 + srow;
    bS[i] = dT + ((size_t)e * H + c) * IN + schunk;
    bD[i] = Bs + (wave * 32 + i * 8) * 64;
  }

  const int la = lane & 15, q = lane >> 4;
  int aoff[2][4], boff[2][4];
#pragma unroll
  for (int s = 0; s < 2; ++s) {
    const int qq = s * 4 + q;
    const int slot = (qq ^ (la & 7)) << 3;
#pragma unroll
    for (int f = 0; f < 4; ++f) {
      aoff[s][f] = (wm * 64 + f * 16 + la) * 64 + slot;
      boff[s][f] = (wn * 64 + f * 16 + la) * 64 + slot;
    }
  }

  f32x4 acc[4][4];
#pragma unroll
  for (int a = 0; a < 4; ++a)
#pragma unroll
    for (int b = 0; b < 4; ++b) acc[a][b] = (f32x4){0.f, 0.f, 0.f, 0.f};

  for (int k0 = 0; k0 < IN; k0 += 64) {
#pragma unroll
    for (int i = 0; i < 4; ++i) {
      gload16(aS[i], aD[i]); aS[i] += 64;
      gload16(bS[i], bD[i]); bS[i] += 64;
    }
    __syncthreads();
#pragma unroll
    for (int s = 0; s < 2; ++s) {
      bf16x8 af[4], bf[4];
#pragma unroll
      for (int f = 0; f < 4; ++f) {
        af[f] = *(const bf16x8*)&As[aoff[s][f]];
        bf[f] = *(const bf16x8*)&Bs[boff[s][f]];
      }
#pragma unroll
      for (int fm = 0; fm < 4; ++fm)
#pragma unroll
        for (int fn = 0; fn < 4; ++fn)
          acc[fm][fn] = __builtin_amdgcn_mfma_f32_16x16x32_bf16(af[fm], bf[fn], acc[fm][fn], 0, 0, 0);
    }
    __syncthreads();
  }

#pragma unroll
  for (int fm = 0; fm < 4; ++fm) {
    const int rbase = wm * 64 + fm * 16 + (q << 2);
#pragma unroll
    for (int j = 0; j < 4; ++j) {
      const int row = m0 + rbase + j;
      if (row < Ce) {
        const int t = tok[base + row];
#pragma unroll
        for (int fn = 0; fn < 4; ++fn) {
          const int col = n0 + wn * 64 + fn * 16 + la;
          atomicAdd(&out[(size_t)t * H + col], acc[fm][fn][j]);
        }
      }
    }
  }
}

extern "C" void kernel_launch(void* const* d_in, const int* in_sizes, int n_in,
                              void* d_out, int out_size, void* d_ws, size_t ws_size,
                              hipStream_t stream) {
  const float* x   = (const float*)d_in[0];
  const float* rw  = (const float*)d_in[1];
  const float* gup = (const float*)d_in[2];
  const float* dwn = (const float*)d_in[3];
  float* out = (float*)d_out;
  const int T = in_sizes[0] / H;  // 1024
  const int P = T * TK;           // 4096

  char* ws = (char*)d_ws;
  int*    cnt    = (int*)(ws + 0);
  int*    cursor = (int*)(ws + 64);
  int*    offs   = (int*)(ws + 128);
  int*    tke    = (int*)(ws + 256);
  float*  tkw    = (float*)(ws + 256 + 4 * (size_t)P);
  int*    tok    = (int*)(ws + 256 + 8 * (size_t)P);
  float*  pw     = (float*)(ws + 256 + 12 * (size_t)P);
  const size_t small_end = 256 + 16 * (size_t)P;

  const size_t xbf_off  = small_end;
  const size_t hbuf_off = xbf_off + (size_t)T * H * 2;
  const size_t gupT_off = hbuf_off + (size_t)P * IN * 2;
  const size_t dT_off   = gupT_off + (size_t)E * I2 * H * 2;
  ushort* xbf  = (ushort*)(ws + xbf_off);
  ushort* hbuf = (ushort*)(ws + hbuf_off);
  ushort* gupT = (ushort*)(ws + gupT_off);
  ushort* dT   = (ushort*)(ws + dT_off);

  hipMemsetAsync(ws, 0, 256, stream);
  hipMemsetAsync(d_out, 0, (size_t)out_size * sizeof(float), stream);

  router_kernel<<<T, 256, 0, stream>>>(x, rw, cnt, tke, tkw);
  scan_kernel<<<1, 64, 0, stream>>>(cnt, offs);
  scatter_kernel<<<P / 256, 256, 0, stream>>>(tke, tkw, offs, cursor, tok, pw);
  tcvt_kernel<<<dim3(I2 / 64, H / 64, E), 256, 0, stream>>>(gup, gupT, H, I2);
  tcvt_kernel<<<dim3(H / 64, IN / 64, E), 256, 0, stream>>>(dwn, dT, IN, H);
  xcvt_kernel<<<(T * H / 4 + 255) / 256, 256, 0, stream>>>(x, xbf, T * H / 4);
  gateup3_kernel<<<dim3(IN / 64, (T + 127) / 128, E), 256, 0, stream>>>(xbf, gupT, offs, tok, pw, hbuf, P);
  down3_kernel<<<dim3(H / 128, (T + 127) / 128, E), 256, 0, stream>>>(hbuf, dT, offs, tok, out, P);
}